// Round 4
// baseline (2560.793 us; speedup 1.0000x reference)
//
#include <hip/hip_runtime.h>

// ---------------------------------------------------------------------------
// BidirectionalMLP equilibrium relaxation on MI355X.
// s1,s2: [256,4096], s3: [256,10].  25 steps of:
//   s1' = clip(0.5*s1 + CC + 0.25*(r2@bw1))          CC = 0.25*(rx@fw0), const
//   s2' = clip(0.5*s2 + 0.25*(r1@fw1) + 0.25*(r3@bw2))
//   s3' = clip((0.5-beta)*s3 + 0.5*(r2@fw2) + beta*y)
// Round 4: weight-stationary restructure. One block per CU owns 32 output
// cols; its 4 waves split K in quarters, each holding B 32x1024 bf16 in 256
// VGPRs. Hot loop = A-frag loads (L2) + MFMA only — no LDS staging, no
// barriers. Cross-wave K-reduction via padded col-major LDS once per step.
// s3 head: blocks 0..7 own 32 rows each (full K inside the block).
// ---------------------------------------------------------------------------

typedef __attribute__((ext_vector_type(4))) float f32x4;
typedef __attribute__((ext_vector_type(8))) short short8;

__device__ __forceinline__ unsigned short f2b(float f) {
    union { float f; unsigned int u; } v;
    v.f = f;
    unsigned int r = v.u + 0x7fffu + ((v.u >> 16) & 1u);
    return (unsigned short)(r >> 16);
}

__device__ __forceinline__ float clamp01(float v) {
    return fminf(fmaxf(v, 0.0f), 1.0f);
}

// ---------------- step kernel (weight-stationary) ----------------
__global__ __launch_bounds__(256, 1) void step_kernel(
    const unsigned short* __restrict__ R2old,
    const unsigned short* __restrict__ R1old,
    const float* __restrict__ S1old, const float* __restrict__ S2old,
    const float* __restrict__ S3old,
    float* __restrict__ S1new, float* __restrict__ S2new, float* __restrict__ S3new,
    unsigned short* __restrict__ R1new, unsigned short* __restrict__ R2new,
    const unsigned short* __restrict__ B1T, const unsigned short* __restrict__ B2T,
    const unsigned short* __restrict__ FW2T,
    const float* __restrict__ CC, const float* __restrict__ bw2,
    const float* __restrict__ y, float beta)
{
    // partial-C buffers, col-major with stride 260 (4-aligned, bank-staggered)
    __shared__ __align__(16) float red[4][32 * 260 + 4];
    __shared__ float s3sh[2560];

    const int tid = threadIdx.x, b = blockIdx.x;
    const bool g1 = (b < 128);
    const int N0 = (g1 ? b : (b - 128)) << 5;
    const unsigned short* __restrict__ A  = g1 ? R2old : R1old;
    const unsigned short* __restrict__ BT = g1 ? B1T : B2T;
    const int wave = tid >> 6, lane = tid & 63, fr = lane & 15, fq = lane >> 4;
    const int kb = wave << 10;            // this wave's K-quarter base

    // ---- B panel (32 cols x 1024 k) into registers: 64 frags ----
    short8 barr[64];
    {
        const unsigned short* bp0 = BT + (size_t)(N0 + fr) * 4096 + kb + fq * 8;
        const unsigned short* bp1 = bp0 + 16 * 4096;
#pragma unroll
        for (int kc = 0; kc < 32; ++kc) {
            barr[kc * 2 + 0] = *(const short8*)(bp0 + kc * 32);
            barr[kc * 2 + 1] = *(const short8*)(bp1 + kc * 32);
        }
    }

    // ---- A-frag voffsets (elements) for 16 m-tiles ----
    int voff[16];
    const int rowk = fr * 4096 + kb + fq * 8;
#pragma unroll
    for (int mt = 0; mt < 16; ++mt) voff[mt] = mt * (16 * 4096) + rowk;

    f32x4 acc[32];
#pragma unroll
    for (int i = 0; i < 32; ++i) acc[i] = (f32x4){0.f, 0.f, 0.f, 0.f};

    // ---- s3 duty: blocks 0..7 own rows [32b, 32b+32) ----
    const bool s3duty = g1 && (b < 8);
    const int s3r0 = b << 5;
    f32x4 acc2[2];
    acc2[0] = (f32x4){0.f, 0.f, 0.f, 0.f}; acc2[1] = acc2[0];
    short8 s3a[2][2], s3f[2];
    int voff20 = 0, voff21 = 0, voffF = 0;
    if (s3duty) {
        voff20 = (s3r0 + fr) * 4096 + kb + fq * 8;
        voff21 = voff20 + 16 * 4096;
        voffF  = fr * 4096 + kb + fq * 8;
        s3a[0][0] = *(const short8*)(A + voff20);
        s3a[0][1] = *(const short8*)(A + voff21);
        s3f[0]    = *(const short8*)(FW2T + voffF);
    }

    // ---- main K loop: 128 groups (kc 0..31 x mg 0..3), 3-stage pipeline ----
    short8 ab[3][4];
#pragma unroll
    for (int mi = 0; mi < 4; ++mi) ab[0][mi] = *(const short8*)(A + voff[mi]);
#pragma unroll
    for (int mi = 0; mi < 4; ++mi) ab[1][mi] = *(const short8*)(A + voff[4 + mi]);

#pragma unroll
    for (int g = 0; g < 128; ++g) {
        const int kc = g >> 2, mg = g & 3;
        if (g + 2 < 128) {
            const int g2 = g + 2, kc2 = g2 >> 2, mg2 = g2 & 3;
#pragma unroll
            for (int mi = 0; mi < 4; ++mi)
                ab[g2 % 3][mi] = *(const short8*)(A + voff[mg2 * 4 + mi] + kc2 * 32);
        }
        if (s3duty && mg == 0 && kc < 31) {   // prefetch s3 operands one kc ahead
            s3a[(kc + 1) & 1][0] = *(const short8*)(A + voff20 + (kc + 1) * 32);
            s3a[(kc + 1) & 1][1] = *(const short8*)(A + voff21 + (kc + 1) * 32);
            s3f[(kc + 1) & 1]    = *(const short8*)(FW2T + voffF + (kc + 1) * 32);
        }
#pragma unroll
        for (int mi = 0; mi < 4; ++mi) {
            const int mt = mg * 4 + mi;
            acc[mt * 2 + 0] = __builtin_amdgcn_mfma_f32_16x16x32_bf16(
                ab[g % 3][mi], barr[kc * 2 + 0], acc[mt * 2 + 0], 0, 0, 0);
            acc[mt * 2 + 1] = __builtin_amdgcn_mfma_f32_16x16x32_bf16(
                ab[g % 3][mi], barr[kc * 2 + 1], acc[mt * 2 + 1], 0, 0, 0);
        }
        if (s3duty && mg == 3) {
            acc2[0] = __builtin_amdgcn_mfma_f32_16x16x32_bf16(
                s3a[kc & 1][0], s3f[kc & 1], acc2[0], 0, 0, 0);
            acc2[1] = __builtin_amdgcn_mfma_f32_16x16x32_bf16(
                s3a[kc & 1][1], s3f[kc & 1], acc2[1], 0, 0, 0);
        }
    }

    // ---- write per-wave partials (col-major, stride 260) ----
#pragma unroll
    for (int mt = 0; mt < 16; ++mt)
#pragma unroll
        for (int nt = 0; nt < 2; ++nt) {
            const int n = nt * 16 + fr, m0 = mt * 16 + fq * 4;
            *(f32x4*)&red[wave][n * 260 + m0] = acc[mt * 2 + nt];
        }
    if (!g1) {
        for (int i = tid; i < 2560; i += 256) s3sh[i] = S3old[i];
    }
    __syncthreads();

    // ---- finalize: wave w owns rows [64w,64w+64); coalesced epilogue ----
    const int c = lane & 31, h = lane >> 5;
    const int rbase = (wave << 6) + (h << 5);
    float bw2r[10];
    if (!g1) {
#pragma unroll
        for (int j = 0; j < 10; ++j) bw2r[j] = bw2[j * 4096 + N0 + c];
    }
#pragma unroll 4
    for (int i = 0; i < 32; ++i) {
        const int r = rbase + i;
        const float sum = red[0][c * 260 + r] + red[1][c * 260 + r]
                        + red[2][c * 260 + r] + red[3][c * 260 + r];
        const size_t o = (size_t)r * 4096 + N0 + c;
        float v;
        if (g1) {
            v = 0.5f * S1old[o] + CC[o] + 0.25f * sum;
        } else {
            float dot = 0.f;
#pragma unroll
            for (int j = 0; j < 10; ++j) dot += s3sh[r * 10 + j] * bw2r[j];
            v = 0.5f * S2old[o] + 0.25f * sum + 0.25f * dot;
        }
        v = clamp01(v);
        if (g1) { S1new[o] = v; R1new[o] = f2b(v); }
        else    { S2new[o] = v; R2new[o] = f2b(v); }
    }

    // ---- s3 head finalize (blocks 0..7 only; block-local barriers) ----
    if (s3duty) {
        __syncthreads();
#pragma unroll
        for (int t = 0; t < 2; ++t)
            *(f32x4*)&red[wave][fr * 260 + t * 16 + fq * 4] = acc2[t];
        __syncthreads();
        if (wave == 0 && lane < 32) {
            const int r = lane;
#pragma unroll
            for (int cc = 0; cc < 10; ++cc) {
                const float s = red[0][cc * 260 + r] + red[1][cc * 260 + r]
                              + red[2][cc * 260 + r] + red[3][cc * 260 + r];
                const int gr = s3r0 + r;
                float v = (0.5f - beta) * S3old[gr * 10 + cc] + 0.5f * s
                        + beta * y[gr * 10 + cc];
                S3new[gr * 10 + cc] = clamp01(v);
            }
        }
    }
}

// ---------------- prep kernels (unchanged from round 3) ----------------
__device__ __forceinline__ void async16(const unsigned short* g, unsigned short* l) {
    __builtin_amdgcn_global_load_lds(
        (__attribute__((address_space(1))) void*)g,
        (__attribute__((address_space(3))) void*)l,
        16, 0, 0);
}

__device__ __forceinline__ short8 frag_ld(const unsigned short* lds, int row, int ksel) {
    int chunk = (row << 3) + (ksel ^ (row & 7));
    return *reinterpret_cast<const short8*>(lds + (chunk << 3));
}

__device__ __forceinline__ void gemm_core(
    const unsigned short* __restrict__ Ag,
    const unsigned short* __restrict__ Bg,
    int K, int M0, int N0,
    unsigned short* ldsA, unsigned short* ldsB,
    f32x4* acc, int tid)
{
    const int lane = tid & 63;
    const int wave = tid >> 6;
    const int wm = (wave >> 1) << 5;
    const int wn = (wave & 1) << 5;
    const int fr = lane & 15;
    const int fq = lane >> 4;
    const int nks = K >> 6;

    for (int ks = 0; ks < nks; ++ks) {
        const int k0 = ks << 6;
        __syncthreads();
#pragma unroll
        for (int r = 0; r < 2; ++r) {
            int ca = (r << 8) + tid;
            int row = ca >> 3, kcs = ca & 7;
            int kc = kcs ^ (row & 7);
            async16(Ag + (size_t)(M0 + row) * K + k0 + (kc << 3), ldsA + (ca << 3));
        }
#pragma unroll
        for (int r = 0; r < 2; ++r) {
            int cb = (r << 8) + tid;
            int row = cb >> 3, kcs = cb & 7;
            int kc = kcs ^ (row & 7);
            async16(Bg + (size_t)(N0 + row) * K + k0 + (kc << 3), ldsB + (cb << 3));
        }
        __syncthreads();
#pragma unroll
        for (int ki = 0; ki < 2; ++ki) {
            const int ksel = (ki << 2) + fq;
            short8 a0 = frag_ld(ldsA, wm + fr, ksel);
            short8 a1 = frag_ld(ldsA, wm + 16 + fr, ksel);
            short8 b0 = frag_ld(ldsB, wn + fr, ksel);
            short8 b1 = frag_ld(ldsB, wn + 16 + fr, ksel);
            acc[0] = __builtin_amdgcn_mfma_f32_16x16x32_bf16(a0, b0, acc[0], 0, 0, 0);
            acc[1] = __builtin_amdgcn_mfma_f32_16x16x32_bf16(a0, b1, acc[1], 0, 0, 0);
            acc[2] = __builtin_amdgcn_mfma_f32_16x16x32_bf16(a1, b0, acc[2], 0, 0, 0);
            acc[3] = __builtin_amdgcn_mfma_f32_16x16x32_bf16(a1, b1, acc[3], 0, 0, 0);
        }
    }
}

// CC = 0.25*(rx @ fw0). A = RX [256,1024] bf16, B = FW0T [4096,1024] bf16.
__global__ __launch_bounds__(256) void c1_kernel(
    const unsigned short* __restrict__ RX,
    const unsigned short* __restrict__ FW0T,
    float* __restrict__ CC)
{
    __shared__ __align__(16) unsigned short ldsA[64 * 64];
    __shared__ __align__(16) unsigned short ldsB[64 * 64];
    const int tid = threadIdx.x;
    const int b = blockIdx.x;
    const int mt = b >> 6, nt = b & 63;
    const int M0 = mt << 6, N0 = nt << 6;

    f32x4 acc[4];
    f32x4 zero = {0.f, 0.f, 0.f, 0.f};
#pragma unroll
    for (int i = 0; i < 4; ++i) acc[i] = zero;

    gemm_core(RX, FW0T, 1024, M0, N0, ldsA, ldsB, acc, tid);

    const int lane = tid & 63;
    const int wave = tid >> 6;
    const int wm = (wave >> 1) << 5;
    const int wn = (wave & 1) << 5;
    const int fr = lane & 15;
    const int fq = lane >> 4;
#pragma unroll
    for (int i = 0; i < 4; ++i) {
        int im = i >> 1, in_ = i & 1;
        int n = N0 + wn + (in_ << 4) + fr;
#pragma unroll
        for (int rr = 0; rr < 4; ++rr) {
            int m = M0 + wm + (im << 4) + (fq << 2) + rr;
            CC[(size_t)m * 4096 + n] = 0.25f * acc[i][rr];
        }
    }
}

// src [R][C] fp32 row-major -> dst [C][R] bf16 (dst row stride = R).
__global__ __launch_bounds__(256) void transpose_cvt(
    const float* __restrict__ src, unsigned short* __restrict__ dst,
    int R, int C)
{
    __shared__ float t[32][33];
    const int c0 = blockIdx.x << 5, r0 = blockIdx.y << 5;
    const int tx = threadIdx.x & 31, ty = threadIdx.x >> 5;
#pragma unroll
    for (int i = 0; i < 32; i += 8)
        t[ty + i][tx] = src[(size_t)(r0 + ty + i) * C + (c0 + tx)];
    __syncthreads();
#pragma unroll
    for (int i = 0; i < 32; i += 8)
        dst[(size_t)(c0 + ty + i) * R + (r0 + tx)] = f2b(t[tx][ty + i]);
}

// FW2T fill, rx convert, zero-init of ping buffers.
__global__ __launch_bounds__(256) void misc_init(
    const float* __restrict__ x, const float* __restrict__ fw2,
    unsigned short* __restrict__ FW2T, unsigned short* __restrict__ RX,
    float* __restrict__ S1, float* __restrict__ S2, float* __restrict__ S3,
    unsigned short* __restrict__ R1, unsigned short* __restrict__ R2)
{
    const int stride = gridDim.x * blockDim.x;
    const int t0 = blockIdx.x * blockDim.x + threadIdx.x;
    for (int i = t0; i < 16 * 4096; i += stride) {
        int n = i >> 12, k = i & 4095;
        FW2T[i] = (n < 10) ? f2b(fw2[k * 10 + n]) : (unsigned short)0;
    }
    for (int i = t0; i < 256 * 1024; i += stride)
        RX[i] = f2b(clamp01(x[i]));
    for (int i = t0; i < 256 * 4096; i += stride) {
        S1[i] = 0.f; S2[i] = 0.f; R1[i] = 0; R2[i] = 0;
    }
    for (int i = t0; i < 2560; i += stride) S3[i] = 0.f;
}

__global__ __launch_bounds__(256) void pack_kernel(
    const float* __restrict__ S1, const float* __restrict__ S2,
    const float* __restrict__ S3, float* __restrict__ out)
{
    const int stride = gridDim.x * blockDim.x;
    for (int i = blockIdx.x * blockDim.x + threadIdx.x; i < 256 * 8202; i += stride) {
        int m = i / 8202, c = i - m * 8202;
        float v;
        if (c < 4096)       v = S1[(size_t)m * 4096 + c];
        else if (c < 8192)  v = S2[(size_t)m * 4096 + (c - 4096)];
        else                v = S3[m * 10 + (c - 8192)];
        out[i] = v;
    }
}

extern "C" void kernel_launch(void* const* d_in, const int* in_sizes, int n_in,
                              void* d_out, int out_size, void* d_ws, size_t ws_size,
                              hipStream_t stream) {
    const float* x   = (const float*)d_in[0];
    const float* fw0 = (const float*)d_in[1];
    const float* fw1 = (const float*)d_in[2];
    const float* fw2 = (const float*)d_in[3];
    // d_in[4] = bw0 : unused by the reference
    const float* bw1 = (const float*)d_in[5];
    const float* bw2 = (const float*)d_in[6];
    const float* y   = (const float*)d_in[7];

    char* ws = (char*)d_ws;
    unsigned short* B1T  = (unsigned short*)(ws + 0);          // 4096x4096 bf16
    unsigned short* B2T  = (unsigned short*)(ws + 33554432);   // 4096x4096 bf16
    unsigned short* FW0T = (unsigned short*)(ws + 67108864);   // 4096x1024 bf16
    unsigned short* FW2T = (unsigned short*)(ws + 75497472);   // 16x4096 bf16
    unsigned short* RX   = (unsigned short*)(ws + 75628544);   // 256x1024 bf16
    float*          CC   = (float*)(ws + 76152832);            // 256x4096 f32
    float*          S1f  = (float*)(ws + 80347136);            // 2 x 256x4096 f32
    float*          S2f  = (float*)(ws + 88735744);            // 2 x 256x4096 f32
    float*          S3f  = (float*)(ws + 97124352);            // 2 x 256x10 f32
    unsigned short* R1   = (unsigned short*)(ws + 97144832);   // 2 x 256x4096 bf16
    unsigned short* R2   = (unsigned short*)(ws + 101339136);  // 2 x 256x4096 bf16

    const size_t SB = 256 * 4096;
    dim3 blk(256);

    transpose_cvt<<<dim3(128, 128), blk, 0, stream>>>(bw1, B1T, 4096, 4096);
    transpose_cvt<<<dim3(128, 128), blk, 0, stream>>>(fw1, B2T, 4096, 4096);
    transpose_cvt<<<dim3(128, 32),  blk, 0, stream>>>(fw0, FW0T, 1024, 4096);
    misc_init<<<512, blk, 0, stream>>>(x, fw2, FW2T, RX,
                                       S1f, S2f, S3f, R1, R2);
    c1_kernel<<<256, blk, 0, stream>>>(RX, FW0T, CC);

    for (int t = 0; t < 25; ++t) {
        const int o = t & 1, nw = o ^ 1;
        const float beta = (t < 20) ? 0.0f : 0.5f;
        step_kernel<<<256, blk, 0, stream>>>(
            R2 + o * SB, R1 + o * SB,
            S1f + o * SB, S2f + o * SB, S3f + o * 2560,
            S1f + nw * SB, S2f + nw * SB, S3f + nw * 2560,
            R1 + nw * SB, R2 + nw * SB,
            B1T, B2T, FW2T, CC, bw2, y, beta);
    }

    pack_kernel<<<2048, blk, 0, stream>>>(S1f + SB, S2f + SB, S3f + 2560,
                                          (float*)d_out);
}